// Round 5
// baseline (259.651 us; speedup 1.0000x reference)
//
#include <hip/hip_runtime.h>
#include <math.h>

#define HH 512
#define WW 512
#define HWp (HH * WW)
#define TT 5
#define CC 5

// conv tiling: 64 x 16 tile, 256 threads, 4 cols x 1 row per thread, NO LDS
#define CTW 64
#define CTH 16
#define NHEADB 168          // head blocks: 672 waves / 4 waves-per-block
#define NCONVB 2048         // 8 x 32 x 8

__device__ float ZBUF[512];   // .bss -> zeros at module load; never written

__device__ __forceinline__ float fast_sigmoid(float x) {
    return __builtin_amdgcn_rcpf(1.0f + __expf(-x));
}

// ---------------- head: one wave owns 64 pixels, all channels ----------------
template<int CIN, int F, int LGF>
__device__ __forceinline__ void head_wave(const float* __restrict__ y,
                                          const float* __restrict__ w,
                                          const float* __restrict__ bias,
                                          float* __restrict__ det,
                                          int b, int chunk, int lane,
                                          float scale, int row_off,
                                          float aw0, float ah0, float aw1, float ah1,
                                          float aw2, float ah2)
{
    const int n   = F * F;
    const int pix = chunk * 64 + lane;

    float acc[21];
    #pragma unroll
    for (int o = 0; o < 21; ++o) acc[o] = bias[o];

    const float* yp = y + (size_t)b * CIN * n + pix;
    for (int c = 0; c < CIN; ++c) {
        float v = yp[(size_t)c * n];              // coalesced across lanes
        #pragma unroll
        for (int o = 0; o < 21; ++o)
            acc[o] = fmaf(v, w[o * CIN + c], acc[o]);   // uniform -> s_load
    }

    const int hy = pix >> LGF;
    const int hx = pix & (F - 1);
    const float inv = 1.0f / 512.0f;
    const float AW[3] = {aw0, aw1, aw2};
    const float AH[3] = {ah0, ah1, ah2};

    #pragma unroll
    for (int a = 0; a < 3; ++a) {
        const int row = row_off + pix * 3 + a;
        float* dp = det + ((size_t)b * 16128 + row) * 7;
        dp[0] = acc[a];
        dp[1] = acc[3 + a * 2];
        dp[2] = acc[4 + a * 2];
        float cx = (fast_sigmoid(acc[9  + a * 4]) + (float)hx) * scale;
        float cy = (fast_sigmoid(acc[10 + a * 4]) + (float)hy) * scale;
        float bw = __expf(acc[11 + a * 4]) * AW[a];
        float bh = __expf(acc[12 + a * 4]) * AH[a];
        dp[3] = (cx - bw * 0.5f) * inv;
        dp[4] = (cy - bh * 0.5f) * inv;
        dp[5] = (cx + bw * 0.5f) * inv;
        dp[6] = (cy + bh * 0.5f) * inv;
    }
}

extern "C" __global__ __launch_bounds__(256, 4)
void spikefpn_fused(const float* __restrict__ x, const float* __restrict__ cw,
                    const float* __restrict__ gamma, const float* __restrict__ beta,
                    const float* __restrict__ cm, const float* __restrict__ vleak,
                    const float* __restrict__ tau, const float* __restrict__ erev,
                    const float* __restrict__ y3, const float* __restrict__ w3, const float* __restrict__ b3,
                    const float* __restrict__ y2, const float* __restrict__ w2, const float* __restrict__ b2,
                    const float* __restrict__ y1, const float* __restrict__ w1, const float* __restrict__ b1,
                    float* __restrict__ out, float* __restrict__ det)
{
    const int bid = blockIdx.x;
    const int tid = threadIdx.x;

    if (bid < NHEADB) {
        // ---------------- head path: wave-independent, no sync ----------------
        const int wid  = bid * 4 + (tid >> 6);   // 0..671
        const int lane = tid & 63;
        if (wid < 512) {
            head_wave<192, 64, 6>(y3, w3, b3, det, wid >> 6, wid & 63, lane,
                                  8.0f, 0, 10.f, 13.f, 16.f, 30.f, 33.f, 23.f);
        } else if (wid < 640) {
            const int sb = wid - 512;
            head_wave<384, 32, 5>(y2, w2, b2, det, sb >> 4, sb & 15, lane,
                                  16.0f, 12288, 30.f, 61.f, 62.f, 45.f, 59.f, 119.f);
        } else {
            const int sb = wid - 640;
            head_wave<768, 16, 4>(y1, w1, b1, det, sb >> 2, sb & 3, lane,
                                  32.0f, 15360, 116.f, 90.f, 156.f, 198.f, 373.f, 326.f);
        }
        return;
    }

    // ---------------- conv + LTC path: no LDS, no barriers ----------------
    const int cb = bid - NHEADB;
    const int bx = cb & 7;
    const int by = (cb >> 3) & 31;
    const int b  = cb >> 8;

    const int tx  = tid & 15;            // col group
    const int ty  = tid >> 4;            // row in tile, 0..15
    const int row = by * CTH + ty;
    const int c0  = bx * CTW + tx * 4;

    const int  cL  = (c0 >= 4) ? c0 - 4 : 0;
    const int  cR  = (c0 + 4 <= 508) ? c0 + 4 : 508;
    const bool vLc = (c0 != 0);
    const bool vRc = (c0 != 508);

    int  rofs[3];
    bool vrow[3];
    #pragma unroll
    for (int dr = 0; dr < 3; ++dr) {
        int rr = row - 1 + dr;
        vrow[dr] = (unsigned)rr < (unsigned)HH;
        rofs[dr] = rr * WW;
    }

    // per-channel params (uniform -> SGPR)
    float g_[CC], be[CC], cmv[CC], vl[CC], tm[CC], er[CC];
    #pragma unroll
    for (int o = 0; o < CC; ++o) {
        g_[o] = gamma[o]; be[o] = beta[o]; cmv[o] = cm[o];
        vl[o] = vleak[o]; tm[o] = tau[o]; er[o] = erev[o];
    }

    const size_t xb = (size_t)b * (TT * CC * HWp);
    const float* zb = ZBUF;

    float vpre[CC][4];
    #pragma unroll
    for (int o = 0; o < CC; ++o)
        #pragma unroll
        for (int j = 0; j < 4; ++j) vpre[o][j] = 0.0f;

    for (int t = 0; t < TT; ++t) {
        const float* xt = x + xb + (size_t)t * (CC * HWp);

        float acc[CC][4];
        #pragma unroll
        for (int o = 0; o < CC; ++o)
            #pragma unroll
            for (int j = 0; j < 4; ++j) acc[o][j] = 0.0f;

        #pragma unroll
        for (int ic = 0; ic < CC; ++ic) {
            const float* xp = xt + ic * HWp;
            float win[3][6];
            #pragma unroll
            for (int dr = 0; dr < 3; ++dr) {
                const float* rp = vrow[dr] ? (xp + rofs[dr]) : zb;   // 2 cndmask
                float4 Lq = *(const float4*)(rp + cL);
                float4 Mq = *(const float4*)(rp + c0);
                float4 Rq = *(const float4*)(rp + cR);
                win[dr][0] = vLc ? Lq.w : 0.0f;
                win[dr][1] = Mq.x;
                win[dr][2] = Mq.y;
                win[dr][3] = Mq.z;
                win[dr][4] = Mq.w;
                win[dr][5] = vRc ? Rq.x : 0.0f;
            }
            #pragma unroll
            for (int oc = 0; oc < CC; ++oc) {
                const float* wp = cw + (oc * CC + ic) * 9;   // uniform -> s_load
                #pragma unroll
                for (int dr = 0; dr < 3; ++dr) {
                    #pragma unroll
                    for (int dc = 0; dc < 3; ++dc) {
                        const float wv = wp[dr * 3 + dc];
                        #pragma unroll
                        for (int j = 0; j < 4; ++j)
                            acc[oc][j] = fmaf(wv, win[dr][j + dc], acc[oc][j]);
                    }
                }
            }
        }

        // ---- LTC update + vectorized store ----
        #pragma unroll
        for (int o = 0; o < CC; ++o) {
            float4 vv;
            float* vp = (float*)&vv;
            #pragma unroll
            for (int j = 0; j < 4; ++j) {
                float wih = fmaf(acc[o][j], g_[o], be[o]);
                float sg  = fast_sigmoid(wih);
                float den = fmaf(cmv[o], sg, vl[o]);
                float num = fmaf(tm[o] * vpre[o][j], __builtin_amdgcn_rcpf(den), wih * er[o]);
                float v   = fast_sigmoid(num);
                vpre[o][j] = v;
                vp[j] = v;
            }
            *(float4*)(out + ((size_t)((b * TT + t) * CC + o)) * HWp + row * WW + c0) = vv;
        }
    }
}

extern "C" void kernel_launch(void* const* d_in, const int* in_sizes, int n_in,
                              void* d_out, int out_size, void* d_ws, size_t ws_size,
                              hipStream_t stream)
{
    const float* x     = (const float*)d_in[0];
    const float* y1    = (const float*)d_in[1];   // [8,768,16,16]
    const float* y2    = (const float*)d_in[2];   // [8,384,32,32]
    const float* y3    = (const float*)d_in[3];   // [8,192,64,64]
    const float* cw    = (const float*)d_in[4];
    const float* gamma = (const float*)d_in[5];
    const float* beta  = (const float*)d_in[6];
    const float* cm    = (const float*)d_in[7];
    const float* vleak = (const float*)d_in[8];
    const float* tau   = (const float*)d_in[9];
    const float* erev  = (const float*)d_in[10];
    const float* w1    = (const float*)d_in[11];
    const float* b1    = (const float*)d_in[12];
    const float* w2    = (const float*)d_in[13];
    const float* b2    = (const float*)d_in[14];
    const float* w3    = (const float*)d_in[15];
    const float* b3    = (const float*)d_in[16];

    float* out = (float*)d_out;
    float* det = out + (size_t)8 * TT * CC * HH * WW;   // 52,428,800

    spikefpn_fused<<<dim3(NHEADB + NCONVB), 256, 0, stream>>>(
        x, cw, gamma, beta, cm, vleak, tau, erev,
        y3, w3, b3, y2, w2, b2, y1, w1, b1, out, det);
}

// Round 6
// 258.006 us; speedup vs baseline: 1.0064x; 1.0064x over previous
//
#include <hip/hip_runtime.h>
#include <math.h>

#define HH 512
#define WW 512
#define HWp (HH * WW)
#define TT 5
#define CC 5

// conv tiling: 64 x 8 tile, 256 threads, 2 cols x 1 row per thread
#define CTW 64
#define CTH 8
#define NROW (CTH + 2)        // 10
#define GCOL 18               // 16B granules per row: cols [gcol0-4, gcol0+68)
#define LCP (GCOL * 4)        // 72 floats per padded row (granule g <-> byte g*16, linear)
#define LDSF (CC * NROW * LCP)   // 3600 floats = 14.4 KB per buffer
#define NG (CC * NROW * GCOL)    // 900 granules
#define NHEADB 168            // 672 head waves / 4 waves-per-block
#define NCONVB 4096           // 8 x 64 x 8

typedef __attribute__((address_space(3))) char       lds_char_t;
typedef __attribute__((address_space(1)))  const char glb_char_t;

__device__ __forceinline__ float fast_sigmoid(float x) {
    return __builtin_amdgcn_rcpf(1.0f + __expf(-x));
}

// ---------------- head: one wave owns 64 pixels, all channels ----------------
template<int CIN, int F, int LGF>
__device__ __forceinline__ void head_wave(const float* __restrict__ y,
                                          const float* __restrict__ w,
                                          const float* __restrict__ bias,
                                          float* __restrict__ det,
                                          int b, int chunk, int lane,
                                          float scale, int row_off,
                                          float aw0, float ah0, float aw1, float ah1,
                                          float aw2, float ah2)
{
    const int n   = F * F;
    const int pix = chunk * 64 + lane;

    float acc[21];
    #pragma unroll
    for (int o = 0; o < 21; ++o) acc[o] = bias[o];

    const float* yp = y + (size_t)b * CIN * n + pix;
    for (int c = 0; c < CIN; ++c) {
        float v = yp[(size_t)c * n];              // coalesced across lanes
        #pragma unroll
        for (int o = 0; o < 21; ++o)
            acc[o] = fmaf(v, w[o * CIN + c], acc[o]);   // uniform -> s_load
    }

    const int hy = pix >> LGF;
    const int hx = pix & (F - 1);
    const float inv = 1.0f / 512.0f;
    const float AW[3] = {aw0, aw1, aw2};
    const float AH[3] = {ah0, ah1, ah2};

    #pragma unroll
    for (int a = 0; a < 3; ++a) {
        const int row = row_off + pix * 3 + a;
        float* dp = det + ((size_t)b * 16128 + row) * 7;
        dp[0] = acc[a];
        dp[1] = acc[3 + a * 2];
        dp[2] = acc[4 + a * 2];
        float cx = (fast_sigmoid(acc[9  + a * 4]) + (float)hx) * scale;
        float cy = (fast_sigmoid(acc[10 + a * 4]) + (float)hy) * scale;
        float bw = __expf(acc[11 + a * 4]) * AW[a];
        float bh = __expf(acc[12 + a * 4]) * AH[a];
        dp[3] = (cx - bw * 0.5f) * inv;
        dp[4] = (cy - bh * 0.5f) * inv;
        dp[5] = (cx + bw * 0.5f) * inv;
        dp[6] = (cy + bh * 0.5f) * inv;
    }
}

extern "C" __global__ __launch_bounds__(256, 5)
void spikefpn_fused(const float* __restrict__ x, const float* __restrict__ cw,
                    const float* __restrict__ gamma, const float* __restrict__ beta,
                    const float* __restrict__ cm, const float* __restrict__ vleak,
                    const float* __restrict__ tau, const float* __restrict__ erev,
                    const float* __restrict__ y3, const float* __restrict__ w3, const float* __restrict__ b3,
                    const float* __restrict__ y2, const float* __restrict__ w2, const float* __restrict__ b2,
                    const float* __restrict__ y1, const float* __restrict__ w1, const float* __restrict__ b1,
                    float* __restrict__ out, float* __restrict__ det)
{
    __shared__ float xs[2 * LDSF];

    const int bid = blockIdx.x;
    const int tid = threadIdx.x;

    if (bid < NHEADB) {
        // ---------------- head path: wave-independent, no sync ----------------
        const int wid  = bid * 4 + (tid >> 6);   // 0..671
        const int lane = tid & 63;
        if (wid < 512) {
            head_wave<192, 64, 6>(y3, w3, b3, det, wid >> 6, wid & 63, lane,
                                  8.0f, 0, 10.f, 13.f, 16.f, 30.f, 33.f, 23.f);
        } else if (wid < 640) {
            const int sb = wid - 512;
            head_wave<384, 32, 5>(y2, w2, b2, det, sb >> 4, sb & 15, lane,
                                  16.0f, 12288, 30.f, 61.f, 62.f, 45.f, 59.f, 119.f);
        } else {
            const int sb = wid - 640;
            head_wave<768, 16, 4>(y1, w1, b1, det, sb >> 2, sb & 3, lane,
                                  32.0f, 15360, 116.f, 90.f, 156.f, 198.f, 373.f, 326.f);
        }
        return;
    }

    // ---------------- conv + LTC: global_load_lds double-buffer ----------------
    const int cb = bid - NHEADB;
    const int bx = cb & 7;            // col tile 0..7
    const int by = (cb >> 3) & 63;    // row tile 0..63
    const int b  = cb >> 9;           // batch

    const int grow0 = by * CTH;
    const int gcol0 = bx * CTW;
    const size_t xb = (size_t)b * (TT * CC * HWp);

    // ---- per-thread staging meta (once) ----
    int  goff[4];
    bool pred[4];
    uint32_t gbase[4];
    #pragma unroll
    for (int k = 0; k < 4; ++k) {
        int g = tid + k * 256;
        bool valid = g < NG;
        int gg  = valid ? g : 0;
        int ch  = gg / (NROW * GCOL);
        int rem = gg - ch * (NROW * GCOL);
        int row = rem / GCOL;
        int c4  = rem - row * GCOL;
        int gr = grow0 + row - 1;
        int gc = gcol0 - 4 + c4 * 4;
        pred[k] = valid && ((unsigned)gr < (unsigned)HH) && ((unsigned)gc < (unsigned)WW);
        goff[k] = ch * HWp + gr * WW + gc;
        gbase[k] = (uint32_t)(((tid & ~63) + k * 256) * 16);   // wave-uniform
        if (valid && !pred[k]) {
            float4 z = make_float4(0.f, 0.f, 0.f, 0.f);
            *(float4*)&xs[g * 4]        = z;
            *(float4*)&xs[LDSF + g * 4] = z;
        }
    }

    lds_char_t* lds0 = (lds_char_t*)xs;

    auto issue_stage = [&](int t, int buf) {
        const float* xt = x + xb + (size_t)t * (CC * HWp);
        const uint32_t bufoff = (uint32_t)buf * (LDSF * 4);
        #pragma unroll
        for (int k = 0; k < 4; ++k) {
            if (pred[k]) {
                __builtin_amdgcn_global_load_lds(
                    (const __attribute__((address_space(1))) void*)(glb_char_t*)(const char*)(xt + goff[k]),
                    (__attribute__((address_space(3))) void*)(lds0 + bufoff + gbase[k]),
                    16, 0, 0);
            }
        }
    };

    // per-channel params (uniform -> SGPR)
    float g_[CC], be[CC], cmv[CC], vl[CC], tm[CC], er[CC];
    #pragma unroll
    for (int o = 0; o < CC; ++o) {
        g_[o] = gamma[o]; be[o] = beta[o]; cmv[o] = cm[o];
        vl[o] = vleak[o]; tm[o] = tau[o]; er[o] = erev[o];
    }

    const int tx = tid & 31;          // col pair: cols 2tx, 2tx+1
    const int ty = tid >> 5;          // row in tile 0..7

    issue_stage(0, 0);
    __syncthreads();

    float vpre[CC][2];
    #pragma unroll
    for (int o = 0; o < CC; ++o) { vpre[o][0] = 0.0f; vpre[o][1] = 0.0f; }

    const int lbase = 2 * tx + 3;     // window col start within padded row

    for (int t = 0; t < TT; ++t) {
        if (t < TT - 1) issue_stage(t + 1, (t + 1) & 1);

        const float* cur = xs + (t & 1) * LDSF;

        float acc[CC][2];
        #pragma unroll
        for (int o = 0; o < CC; ++o) { acc[o][0] = 0.0f; acc[o][1] = 0.0f; }

        #pragma unroll
        for (int ic = 0; ic < CC; ++ic) {
            float win[3][4];
            #pragma unroll
            for (int dr = 0; dr < 3; ++dr) {
                const float* lp = &cur[(ic * NROW + ty + dr) * LCP + lbase];
                win[dr][0] = lp[0]; win[dr][1] = lp[1];
                win[dr][2] = lp[2]; win[dr][3] = lp[3];
            }
            #pragma unroll
            for (int oc = 0; oc < CC; ++oc) {
                const float* wp = cw + (oc * CC + ic) * 9;   // uniform -> s_load
                float a0 = acc[oc][0], a1 = acc[oc][1];
                #pragma unroll
                for (int dr = 0; dr < 3; ++dr)
                    #pragma unroll
                    for (int dc = 0; dc < 3; ++dc) {
                        const float wv = wp[dr * 3 + dc];
                        a0 = fmaf(wv, win[dr][dc],     a0);
                        a1 = fmaf(wv, win[dr][dc + 1], a1);
                    }
                acc[oc][0] = a0; acc[oc][1] = a1;
            }
        }

        // ---- LTC update + float2 store ----
        const size_t obase = (size_t)(grow0 + ty) * WW + gcol0 + 2 * tx;
        #pragma unroll
        for (int o = 0; o < CC; ++o) {
            float2 vv;
            #pragma unroll
            for (int j = 0; j < 2; ++j) {
                float wih = fmaf(acc[o][j], g_[o], be[o]);
                float sg  = fast_sigmoid(wih);
                float den = fmaf(cmv[o], sg, vl[o]);
                float num = fmaf(tm[o] * vpre[o][j], __builtin_amdgcn_rcpf(den), wih * er[o]);
                float v   = fast_sigmoid(num);
                vpre[o][j] = v;
                (&vv.x)[j] = v;
            }
            *(float2*)(out + ((size_t)((b * TT + t) * CC + o)) * HWp + obase) = vv;
        }

        if (t < TT - 1) __syncthreads();   // drains vmcnt: t+1 loads landed
    }
}

extern "C" void kernel_launch(void* const* d_in, const int* in_sizes, int n_in,
                              void* d_out, int out_size, void* d_ws, size_t ws_size,
                              hipStream_t stream)
{
    const float* x     = (const float*)d_in[0];
    const float* y1    = (const float*)d_in[1];   // [8,768,16,16]
    const float* y2    = (const float*)d_in[2];   // [8,384,32,32]
    const float* y3    = (const float*)d_in[3];   // [8,192,64,64]
    const float* cw    = (const float*)d_in[4];
    const float* gamma = (const float*)d_in[5];
    const float* beta  = (const float*)d_in[6];
    const float* cm    = (const float*)d_in[7];
    const float* vleak = (const float*)d_in[8];
    const float* tau   = (const float*)d_in[9];
    const float* erev  = (const float*)d_in[10];
    const float* w1    = (const float*)d_in[11];
    const float* b1    = (const float*)d_in[12];
    const float* w2    = (const float*)d_in[13];
    const float* b2    = (const float*)d_in[14];
    const float* w3    = (const float*)d_in[15];
    const float* b3    = (const float*)d_in[16];

    float* out = (float*)d_out;
    float* det = out + (size_t)8 * TT * CC * HH * WW;   // 52,428,800

    spikefpn_fused<<<dim3(NHEADB + NCONVB), 256, 0, stream>>>(
        x, cw, gamma, beta, cm, vleak, tau, erev,
        y3, w3, b3, y2, w2, b2, y1, w1, b1, out, det);
}

// Round 7
// 169.393 us; speedup vs baseline: 1.5328x; 1.5231x over previous
//
#include <hip/hip_runtime.h>
#include <math.h>

#define HH 512
#define WW 512
#define HWp (HH * WW)
#define TT 5
#define CC 5

// conv tiling: 64 x 16 tile, 512 threads, 1 col x 2 rows per thread
#define CTW 64
#define CTH 16
#define NROW (CTH + 2)        // 18
#define GCOL 18               // 16B granules per padded row: cols [gcol0-4, gcol0+68)
#define LCP (GCOL * 4)        // 72 floats per padded row (granule g <-> byte g*16, linear)
#define LDSF (CC * NROW * LCP)   // 6480 floats = 25920 B per buffer
#define NG (CC * NROW * GCOL)    // 1620 granules
#define NBUF 3
#define SPARE_BYTES (NBUF * LDSF * 4)   // dump slot for dummy loads (1 KB)

typedef __attribute__((address_space(3))) char       lds_char_t;
typedef __attribute__((address_space(1)))  const char glb_char_t;

__device__ __forceinline__ float fast_sigmoid(float x) {
    return __builtin_amdgcn_rcpf(1.0f + __expf(-x));
}

extern "C" __global__ __launch_bounds__(512, 4)
void conv_ltc_kernel(const float* __restrict__ x, const float* __restrict__ cw,
                     const float* __restrict__ gamma, const float* __restrict__ beta,
                     const float* __restrict__ cm, const float* __restrict__ vleak,
                     const float* __restrict__ tau, const float* __restrict__ erev,
                     float* __restrict__ out)
{
    __shared__ float xs[NBUF * LDSF + 256];

    const int tid = threadIdx.x;
    const int bx = blockIdx.x;   // col tile 0..7
    const int by = blockIdx.y;   // row tile 0..31
    const int b  = blockIdx.z;   // batch

    const int grow0 = by * CTH;
    const int gcol0 = bx * CTW;
    const size_t xb = (size_t)b * (TT * CC * HWp);

    // ---- per-thread staging meta (once). Every wave issues EXACTLY 4 loads/stage.
    int  goff[4];
    bool pred[4];
    uint32_t gbase[4];
    #pragma unroll
    for (int k = 0; k < 4; ++k) {
        const int g = tid + k * 512;
        const int wavebase = (tid & ~63) + k * 512;
        if (wavebase >= NG) {
            // whole wave-group invalid -> dummy load to spare slot (keeps vmcnt uniform)
            pred[k] = true;
            goff[k] = 0;
            gbase[k] = (uint32_t)SPARE_BYTES;
        } else {
            const bool valid = g < NG;
            const int gg  = valid ? g : 0;
            const int ch  = gg / (NROW * GCOL);
            const int rem = gg - ch * (NROW * GCOL);
            const int row = rem / GCOL;
            const int c4  = rem - row * GCOL;
            const int gr = grow0 + row - 1;
            const int gc = gcol0 - 4 + c4 * 4;
            const bool inb = valid && ((unsigned)gr < (unsigned)HH) && ((unsigned)gc < (unsigned)WW);
            pred[k] = inb;
            goff[k] = ch * HWp + gr * WW + gc;
            gbase[k] = (uint32_t)(wavebase * 16);   // wave-uniform LDS base
            if (valid && !inb) {
                // OOB halo: zero once in all three buffers; loads never touch these
                float4 z = make_float4(0.f, 0.f, 0.f, 0.f);
                *(float4*)&xs[g * 4]            = z;
                *(float4*)&xs[LDSF + g * 4]     = z;
                *(float4*)&xs[2 * LDSF + g * 4] = z;
            }
        }
    }

    lds_char_t* lds0 = (lds_char_t*)xs;

    auto issue_stage = [&](int t, int buf) {
        const float* xt = x + xb + (size_t)t * (CC * HWp);
        const uint32_t bufoff = (uint32_t)buf * (LDSF * 4);
        #pragma unroll
        for (int k = 0; k < 4; ++k) {
            if (pred[k]) {
                __builtin_amdgcn_global_load_lds(
                    (const __attribute__((address_space(1))) void*)(glb_char_t*)(const char*)(xt + goff[k]),
                    (__attribute__((address_space(3))) void*)(lds0 + bufoff + gbase[k]),
                    16, 0, 0);
            }
        }
    };

    // per-channel params (uniform -> SGPR)
    float g_[CC], be[CC], cmv[CC], vl[CC], tm[CC], er[CC];
    #pragma unroll
    for (int o = 0; o < CC; ++o) {
        g_[o] = gamma[o]; be[o] = beta[o]; cmv[o] = cm[o];
        vl[o] = vleak[o]; tm[o] = tau[o]; er[o] = erev[o];
    }

    const int tx = tid & 63;          // col 0..63
    const int r0 = (tid >> 6) * 2;    // rows r0, r0+1 (wave-uniform)

    // ---- prologue: stage t0 -> buf0, t1 -> buf1; wait only t0 (vmcnt(4)) ----
    issue_stage(0, 0);
    issue_stage(1, 1);
    asm volatile("s_waitcnt vmcnt(4)" ::: "memory");
    asm volatile("s_waitcnt lgkmcnt(0)" ::: "memory");   // zero-fill writes visible
    __builtin_amdgcn_s_barrier();
    __builtin_amdgcn_sched_barrier(0);

    float vpre[2][CC];
    #pragma unroll
    for (int r = 0; r < 2; ++r)
        #pragma unroll
        for (int o = 0; o < CC; ++o) vpre[r][o] = 0.0f;

    #pragma unroll
    for (int t = 0; t < TT; ++t) {
        if (t + 2 < TT) issue_stage(t + 2, (t + 2) % NBUF);   // 2-deep prefetch

        const float* cur = xs + (t % NBUF) * LDSF;

        float acc[2][CC];
        #pragma unroll
        for (int r = 0; r < 2; ++r)
            #pragma unroll
            for (int o = 0; o < CC; ++o) acc[r][o] = 0.0f;

        #pragma unroll
        for (int ic = 0; ic < CC; ++ic) {
            float rv[4][3];
            #pragma unroll
            for (int dr = 0; dr < 4; ++dr) {
                const float* lp = &cur[(ic * NROW + (r0 + dr)) * LCP + tx + 3];
                rv[dr][0] = lp[0]; rv[dr][1] = lp[1]; rv[dr][2] = lp[2];
            }
            #pragma unroll
            for (int oc = 0; oc < CC; ++oc) {
                const float* wp = cw + (oc * CC + ic) * 9;   // uniform -> s_load
                float wv[9];
                #pragma unroll
                for (int k = 0; k < 9; ++k) wv[k] = wp[k];
                float a0 = acc[0][oc], a1 = acc[1][oc];
                #pragma unroll
                for (int dr = 0; dr < 3; ++dr)
                    #pragma unroll
                    for (int dc = 0; dc < 3; ++dc) {
                        a0 = fmaf(wv[dr * 3 + dc], rv[dr][dc],     a0);
                        a1 = fmaf(wv[dr * 3 + dc], rv[dr + 1][dc], a1);
                    }
                acc[0][oc] = a0; acc[1][oc] = a1;
            }
        }

        // ---- LTC update + store (2 rows x 5 ch = 10 stores) ----
        #pragma unroll
        for (int r = 0; r < 2; ++r) {
            const int grow = grow0 + r0 + r;
            const size_t ob = (size_t)grow * WW + gcol0 + tx;
            #pragma unroll
            for (int o = 0; o < CC; ++o) {
                float wih = fmaf(acc[r][o], g_[o], be[o]);
                float sg  = fast_sigmoid(wih);
                float den = fmaf(cmv[o], sg, vl[o]);
                float num = fmaf(tm[o] * vpre[r][o], __builtin_amdgcn_rcpf(den), wih * er[o]);
                float v   = fast_sigmoid(num);
                vpre[r][o] = v;
                out[((size_t)((b * TT + t) * CC + o)) * HWp + ob] = v;
            }
        }

        // ---- counted waits: keep next-next loads in flight across the barrier ----
        if (t <= 2) {
            // FIFO: S(t+1) | stores(t-1..) | S(t+2):4 | stores(t):10 -> 14 youngest stay
            asm volatile("s_waitcnt vmcnt(14)" ::: "memory");
            __builtin_amdgcn_s_barrier();
            __builtin_amdgcn_sched_barrier(0);
        } else if (t == 3) {
            // FIFO: S(4):4 | stores(2) | stores(3):10 -> need S(4) done
            asm volatile("s_waitcnt vmcnt(10)" ::: "memory");
            __builtin_amdgcn_s_barrier();
            __builtin_amdgcn_sched_barrier(0);
        }
    }
}

// ---------------- fused detection head + decode, all 3 scales ----------------
#define SMEM_F 18432   // max(768*24, 512*21)

extern "C" __global__ __launch_bounds__(512)
void head_fused_kernel(const float* __restrict__ y3, const float* __restrict__ w3, const float* __restrict__ b3,
                       const float* __restrict__ y2, const float* __restrict__ w2, const float* __restrict__ b2,
                       const float* __restrict__ y1, const float* __restrict__ w1, const float* __restrict__ b1,
                       float* __restrict__ det)
{
    __shared__ float smem[SMEM_F];

    const int bid = blockIdx.x;
    const float *y, *w, *bias;
    int Cin, f, lgf, lgchunks, row_off;
    float s;
    float aw0, aw1, aw2, ah0, ah1, ah2;
    int sb;

    if (bid < 512) {
        sb = bid;       y = y3; w = w3; bias = b3; Cin = 192; f = 64; lgf = 6; lgchunks = 6; s = 8.0f;  row_off = 0;
        aw0 = 10.f;  ah0 = 13.f;  aw1 = 16.f;  ah1 = 30.f;  aw2 = 33.f;  ah2 = 23.f;
    } else if (bid < 640) {
        sb = bid - 512; y = y2; w = w2; bias = b2; Cin = 384; f = 32; lgf = 5; lgchunks = 4; s = 16.0f; row_off = 12288;
        aw0 = 30.f;  ah0 = 61.f;  aw1 = 62.f;  ah1 = 45.f;  aw2 = 59.f;  ah2 = 119.f;
    } else {
        sb = bid - 640; y = y1; w = w1; bias = b1; Cin = 768; f = 16; lgf = 4; lgchunks = 2; s = 32.0f; row_off = 15360;
        aw0 = 116.f; ah0 = 90.f;  aw1 = 156.f; ah1 = 198.f; aw2 = 373.f; ah2 = 326.f;
    }

    const int n     = f * f;
    const int b     = sb >> lgchunks;
    const int chunk = sb & ((1 << lgchunks) - 1);

    const int tid  = threadIdx.x;
    const int lane = tid & 63;
    const int grp  = tid >> 6;          // 0..7

    // ---- stage wT (padded rows of 24) into LDS ----
    const int wtot = Cin * 21;
    for (int i = tid; i < wtot; i += 512) {
        int o = i / Cin;
        int c = i - o * Cin;
        smem[c * 24 + o] = w[i];
    }
    __syncthreads();

    const int G   = Cin >> 3;
    const int pix = (chunk << 6) + lane;

    float acc[21];
    #pragma unroll
    for (int o = 0; o < 21; ++o) acc[o] = 0.0f;

    const float* yp = y + ((size_t)b * Cin + (size_t)grp * G) * n + pix;
    const int wbase = grp * G * 24;

    #pragma unroll 4
    for (int c = 0; c < G; ++c) {
        float v = yp[(size_t)c * n];                     // coalesced
        const float* wr = &smem[wbase + c * 24];         // wave-uniform -> broadcast
        float4 q0 = *(const float4*)(wr);
        float4 q1 = *(const float4*)(wr + 4);
        float4 q2 = *(const float4*)(wr + 8);
        float4 q3 = *(const float4*)(wr + 12);
        float4 q4 = *(const float4*)(wr + 16);
        float  s20 = wr[20];
        float wv[21] = {q0.x,q0.y,q0.z,q0.w, q1.x,q1.y,q1.z,q1.w,
                        q2.x,q2.y,q2.z,q2.w, q3.x,q3.y,q3.z,q3.w,
                        q4.x,q4.y,q4.z,q4.w, s20};
        #pragma unroll
        for (int o = 0; o < 21; ++o) acc[o] = fmaf(v, wv[o], acc[o]);
    }
    __syncthreads();   // all reads of wT done; smem reused for reduction

    #pragma unroll
    for (int o = 0; o < 21; ++o) smem[tid * 21 + o] = acc[o];
    __syncthreads();

    if (tid < 64) {
        float r[21];
        #pragma unroll
        for (int o = 0; o < 21; ++o) r[o] = bias[o];
        #pragma unroll
        for (int g2 = 0; g2 < 8; ++g2) {
            const float* rp = &smem[(g2 * 64 + lane) * 21];
            #pragma unroll
            for (int o = 0; o < 21; ++o) r[o] += rp[o];
        }

        const int hy = pix >> lgf;
        const int hx = pix & (f - 1);
        const float inv = 1.0f / 512.0f;
        const float AW[3] = {aw0, aw1, aw2};
        const float AH[3] = {ah0, ah1, ah2};

        #pragma unroll
        for (int a = 0; a < 3; ++a) {
            const int row = row_off + pix * 3 + a;
            float* dp = det + ((size_t)b * 16128 + row) * 7;
            dp[0] = r[a];
            dp[1] = r[3 + a * 2];
            dp[2] = r[4 + a * 2];
            float txv = r[9  + a * 4];
            float tyv = r[10 + a * 4];
            float twv = r[11 + a * 4];
            float thv = r[12 + a * 4];
            float cx = (fast_sigmoid(txv) + (float)hx) * s;
            float cy = (fast_sigmoid(tyv) + (float)hy) * s;
            float bw = __expf(twv) * AW[a];
            float bh = __expf(thv) * AH[a];
            dp[3] = (cx - bw * 0.5f) * inv;
            dp[4] = (cy - bh * 0.5f) * inv;
            dp[5] = (cx + bw * 0.5f) * inv;
            dp[6] = (cy + bh * 0.5f) * inv;
        }
    }
}

extern "C" void kernel_launch(void* const* d_in, const int* in_sizes, int n_in,
                              void* d_out, int out_size, void* d_ws, size_t ws_size,
                              hipStream_t stream)
{
    const float* x     = (const float*)d_in[0];
    const float* y1    = (const float*)d_in[1];   // [8,768,16,16]
    const float* y2    = (const float*)d_in[2];   // [8,384,32,32]
    const float* y3    = (const float*)d_in[3];   // [8,192,64,64]
    const float* cw    = (const float*)d_in[4];
    const float* gamma = (const float*)d_in[5];
    const float* beta  = (const float*)d_in[6];
    const float* cm    = (const float*)d_in[7];
    const float* vleak = (const float*)d_in[8];
    const float* tau   = (const float*)d_in[9];
    const float* erev  = (const float*)d_in[10];
    const float* w1    = (const float*)d_in[11];
    const float* b1    = (const float*)d_in[12];
    const float* w2    = (const float*)d_in[13];
    const float* b2    = (const float*)d_in[14];
    const float* w3    = (const float*)d_in[15];
    const float* b3    = (const float*)d_in[16];

    float* out = (float*)d_out;
    float* det = out + (size_t)8 * TT * CC * HH * WW;   // 52,428,800

    dim3 cgrid(WW / CTW, HH / CTH, 8);     // 8 x 32 x 8
    conv_ltc_kernel<<<cgrid, 512, 0, stream>>>(x, cw, gamma, beta, cm, vleak, tau, erev, out);

    head_fused_kernel<<<dim3(672), 512, 0, stream>>>(y3, w3, b3, y2, w2, b2, y1, w1, b1, det);
}